// Round 10
// baseline (423.641 us; speedup 1.0000x reference)
//
#include <hip/hip_runtime.h>

#define T_ 2
#define N_ 4096
#define E_ 4096
#define D_ 128
#define CAP 64
#define D4 (D_ / 4)   // 32 float4 per f32 feature row
#define DB2 (D_ / 4)  // 32 uint2 (4 bf16 each) per bf16 feature row

// ---------------------------------------------------------------------------
// bf16 helpers (RNE pack, bit-exact unpack)
__device__ __forceinline__ unsigned f2bf_rne(float f) {
    unsigned u = __float_as_uint(f);
    return (u + 0x7FFFu + ((u >> 16) & 1u)) >> 16;
}
__device__ __forceinline__ unsigned pack2(float lo, float hi) {
    return f2bf_rne(lo) | (f2bf_rne(hi) << 16);
}
__device__ __forceinline__ void acc_bf4(float4& s, uint2 a) {
    s.x += __uint_as_float(a.x << 16);
    s.y += __uint_as_float(a.x & 0xFFFF0000u);
    s.z += __uint_as_float(a.y << 16);
    s.w += __uint_as_float(a.y & 0xFFFF0000u);
}

// ---------------------------------------------------------------------------
// scan body (one wave per row)
__device__ __forceinline__ void scan_row(int row, int lane,
        const float* __restrict__ H, float* __restrict__ dVis,
        int* __restrict__ cntNE, int* __restrict__ adjNE) {
    const float4* row4 = (const float4*)(H + (size_t)row * E_);
    unsigned long long mask = 0;
    #pragma unroll
    for (int i = 0; i < 16; ++i) {
        float4 v = row4[i * 64 + lane];
        unsigned mm = 0;
        if (v.x != 0.0f) mm |= 1u;
        if (v.y != 0.0f) mm |= 2u;
        if (v.z != 0.0f) mm |= 4u;
        if (v.w != 0.0f) mm |= 8u;
        mask |= (unsigned long long)mm << (i * 4);
    }
    int cnt = __popcll(mask);
    int incl = cnt;
    #pragma unroll
    for (int off = 1; off < 64; off <<= 1) {
        int u = __shfl_up(incl, off);
        if (lane >= off) incl += u;
    }
    int pos = incl - cnt;
    int* adjrow = adjNE + (size_t)row * CAP;
    unsigned long long m = mask;
    while (m) {
        int bpos = __builtin_ctzll(m);
        m &= m - 1;
        int e = ((bpos >> 2) << 8) + lane * 4 + (bpos & 3);
        if (pos < CAP) adjrow[pos] = e;
        ++pos;
    }
    if (lane == 63) {
        cntNE[row] = incl < CAP ? incl : CAP;
        dVis[row] = incl > 0 ? rsqrtf((float)incl) : 0.0f;
    }
}

__global__ __launch_bounds__(256) void k_scan(const float* __restrict__ H,
        float* __restrict__ dVis, int* __restrict__ cntNE,
        int* __restrict__ adjNE, int* __restrict__ cntENp) {
    int row = blockIdx.x * 4 + (threadIdx.x >> 6);
    int lane = threadIdx.x & 63;
    if (lane == 0) cntENp[row * 16] = 0;
    scan_row(row, lane, H, dVis, cntNE, adjNE);
}

// PROBE: 4x scan work into shadow buffers (rows remapped per iter)
__global__ __launch_bounds__(256) void k_scan_probe(const float* __restrict__ H,
        float* __restrict__ dVis_sh, int* __restrict__ cntNE_sh,
        int* __restrict__ adjNE_sh) {
    int base = blockIdx.x * 4 + (threadIdx.x >> 6);
    int lane = threadIdx.x & 63;
    for (int r = 0; r < 4; ++r) {
        int row = (base + r * 2011) & (T_ * N_ - 1);
        scan_row(row, lane, H, dVis_sh, cntNE_sh, adjNE_sh);
    }
}

// ---------------------------------------------------------------------------
// xw tile body
__device__ __forceinline__ void xw_tile(int slot, int l,
        const float* __restrict__ xsrc, const float* __restrict__ W,
        const float* __restrict__ b, const float* __restrict__ dVis,
        uint2* __restrict__ y2, float* s_xs, float* s_ws) {
    int t = slot >> 7;
    int nb = (slot >> 1) & 63, ob = slot & 1;
    int n0 = nb * 64, o0 = ob * 64;
    int tid = threadIdx.x;
    int tx = tid & 15, ty = tid >> 4;
    const float* Wg = W + ((size_t)(l * T_ + t) * D_ + o0) * D_;
    const float* xg = xsrc + (size_t)n0 * D_;
    float acc[4][4] = {};
    for (int kc = 0; kc < 4; ++kc) {
        __syncthreads();
        for (int i = tid; i < 512; i += 256) {
            int r = i >> 3, k4 = i & 7;
            *(float4*)(s_xs + r * 36 + k4 * 4) =
                *(const float4*)(xg + (size_t)r * D_ + kc * 32 + k4 * 4);
            int k4s = k4 ^ ((r >> 2) & 7);
            *(float4*)(s_ws + r * 32 + k4s * 4) =
                *(const float4*)(Wg + (size_t)r * D_ + kc * 32 + k4 * 4);
        }
        __syncthreads();
        #pragma unroll
        for (int k4 = 0; k4 < 8; ++k4) {
            float4 xv[4], wv[4];
            #pragma unroll
            for (int rr = 0; rr < 4; ++rr)
                xv[rr] = *(const float4*)(s_xs + (ty * 4 + rr) * 36 + k4 * 4);
            int k4s = k4 ^ (tx & 7);
            #pragma unroll
            for (int cc = 0; cc < 4; ++cc)
                wv[cc] = *(const float4*)(s_ws + (tx * 4 + cc) * 32 + k4s * 4);
            #pragma unroll
            for (int rr = 0; rr < 4; ++rr)
                #pragma unroll
                for (int cc = 0; cc < 4; ++cc)
                    acc[rr][cc] += xv[rr].x * wv[cc].x + xv[rr].y * wv[cc].y
                                 + xv[rr].z * wv[cc].z + xv[rr].w * wv[cc].w;
        }
    }
    const float* bg = b + (size_t)(l * T_ + t) * D_;
    float4 bv = *(const float4*)(bg + o0 + tx * 4);
    #pragma unroll
    for (int rr = 0; rr < 4; ++rr) {
        int n = n0 + ty * 4 + rr;
        float s = dVis[t * N_ + n];
        uint2 ov;
        ov.x = pack2(s * (acc[rr][0] + bv.x), s * (acc[rr][1] + bv.y));
        ov.y = pack2(s * (acc[rr][2] + bv.z), s * (acc[rr][3] + bv.w));
        y2[(size_t)(t * N_ + n) * DB2 + (o0 >> 2) + tx] = ov;
    }
}

__global__ __launch_bounds__(256) void k_inv_xw0(const int* __restrict__ cntNE,
        const int* __restrict__ adjNE, int* __restrict__ cntENp,
        int* __restrict__ adjEN,
        const float* __restrict__ x, const float* __restrict__ W,
        const float* __restrict__ b, const float* __restrict__ dVis,
        uint2* __restrict__ y2) {
    __shared__ float s_xs[64 * 36];
    __shared__ float s_ws[64 * 32];
    int bid = blockIdx.x;
    if (bid < 2048) {
        int row = bid * 4 + (threadIdx.x >> 6);
        int lane = threadIdx.x & 63;
        int t = row >> 12;
        int n_id = row & (N_ - 1);
        int c = cntNE[row];
        if (lane < c) {
            int e = adjNE[(size_t)row * CAP + lane];
            int slot = atomicAdd(&cntENp[(t * E_ + e) * 16], 1);
            if (slot < CAP) adjEN[((size_t)(t * E_ + e)) * CAP + slot] = n_id;
        }
    } else {
        xw_tile(bid - 2048, 0, x, W, b, dVis, y2, s_xs, s_ws);
    }
}

__global__ __launch_bounds__(256) void k_xw1(const float* __restrict__ xsrc,
        const float* __restrict__ W, const float* __restrict__ b,
        const float* __restrict__ dVis, uint2* __restrict__ y2) {
    __shared__ float s_xs[64 * 36];
    __shared__ float s_ws[64 * 32];
    xw_tile(blockIdx.x, 1, xsrc, W, b, dVis, y2, s_xs, s_ws);
}

// ---------------------------------------------------------------------------
// bf16 gather core
__device__ __forceinline__ float4 gather_sum_bf(const uint2* __restrict__ src,
        const int* __restrict__ row, int c, int q) {
    float4 s = {0.f, 0.f, 0.f, 0.f};
    for (int j0 = 0; j0 < c; j0 += 4) {
        int4 ids = *reinterpret_cast<const int4*>(row + j0);
        acc_bf4(s, src[(size_t)ids.x * DB2 + q]);
        if (j0 + 1 < c) acc_bf4(s, src[(size_t)ids.y * DB2 + q]);
        if (j0 + 2 < c) acc_bf4(s, src[(size_t)ids.z * DB2 + q]);
        if (j0 + 3 < c) acc_bf4(s, src[(size_t)ids.w * DB2 + q]);
    }
    return s;
}

__device__ __forceinline__ void ye_one(int vr, int q, const uint2* __restrict__ y2,
        const int* __restrict__ cntENp, const int* __restrict__ adjEN,
        uint2* __restrict__ ye2) {
    int t = vr >> 12;
    int c = cntENp[vr * 16];
    if (c > CAP) c = CAP;
    float dE = c > 0 ? 1.0f / (float)c : 0.0f;
    float4 s = gather_sum_bf(y2 + (size_t)t * N_ * DB2, adjEN + (size_t)vr * CAP, c, q);
    uint2 o;
    o.x = pack2(dE * s.x, dE * s.y);
    o.y = pack2(dE * s.z, dE * s.w);
    ye2[(size_t)vr * DB2 + q] = o;
}

__device__ __forceinline__ void o_one(int e, int q, const uint2* __restrict__ e2,
        const int* __restrict__ cntENp, const int* __restrict__ adjEN,
        float4* __restrict__ revacc4, float4* __restrict__ outrev4, int last) {
    float4 acc = {0.f, 0.f, 0.f, 0.f};
    #pragma unroll
    for (int t = 0; t < T_; ++t) {
        int r = t * E_ + e;
        int c = cntENp[r * 16];
        if (c > CAP) c = CAP;
        float dE = c > 0 ? 1.0f / (float)c : 0.0f;
        float4 s = gather_sum_bf(e2 + (size_t)t * N_ * DB2, adjEN + (size_t)r * CAP, c, q);
        acc.x += dE * s.x; acc.y += dE * s.y; acc.z += dE * s.z; acc.w += dE * s.w;
    }
    size_t i = (size_t)e * D4 + q;
    if (!last) revacc4[i] = acc;
    else {
        float4 ra = revacc4[i];
        float4 o = {(ra.x + acc.x) * 0.5f, (ra.y + acc.y) * 0.5f,
                    (ra.z + acc.z) * 0.5f, (ra.w + acc.w) * 0.5f};
        outrev4[i] = o;
    }
}

__device__ __forceinline__ void e_work(int n, int q, const uint2* __restrict__ ye2,
        const float* __restrict__ dVis, const int* __restrict__ cntNE,
        const int* __restrict__ adjNE, uint2* __restrict__ e2,
        const float* __restrict__ x0, float* __restrict__ xsum0,
        float* __restrict__ outnode, int last) {
    float4 xnew = {0.f, 0.f, 0.f, 0.f};
    #pragma unroll
    for (int t = 0; t < T_; ++t) {
        int r = t * N_ + n;
        int c = cntNE[r];
        float4 s = gather_sum_bf(ye2 + (size_t)t * E_ * DB2, adjNE + (size_t)r * CAP, c, q);
        float dv = dVis[r];
        float4 ev;
        ev.x = dv * s.x; ev.x = ev.x >= 0.f ? ev.x : 0.01f * ev.x;
        ev.y = dv * s.y; ev.y = ev.y >= 0.f ? ev.y : 0.01f * ev.y;
        ev.z = dv * s.z; ev.z = ev.z >= 0.f ? ev.z : 0.01f * ev.z;
        ev.w = dv * s.w; ev.w = ev.w >= 0.f ? ev.w : 0.01f * ev.w;
        uint2 ep;
        ep.x = pack2(ev.x, ev.y);
        ep.y = pack2(ev.z, ev.w);
        e2[(size_t)r * DB2 + q] = ep;
        xnew.x += ev.x; xnew.y += ev.y; xnew.z += ev.z; xnew.w += ev.w;
    }
    size_t i = (size_t)n * D4 + q;
    if (!last) ((float4*)xsum0)[i] = xnew;
    else {
        float4 xv = ((const float4*)x0)[i];
        float4 xs = ((const float4*)xsum0)[i];
        float4 o = {(xv.x + xs.x + xnew.x) * (1.0f / 3.0f),
                    (xv.y + xs.y + xnew.y) * (1.0f / 3.0f),
                    (xv.z + xs.z + xnew.z) * (1.0f / 3.0f),
                    (xv.w + xs.w + xnew.w) * (1.0f / 3.0f)};
        ((float4*)outnode)[i] = o;
    }
}

// ---------------------------------------------------------------------------
// real chain kernels
__global__ __launch_bounds__(256) void k_ye(const uint2* __restrict__ y2,
        const int* __restrict__ cntENp, const int* __restrict__ adjEN,
        uint2* __restrict__ ye2) {
    int vr = blockIdx.x * 8 + (threadIdx.x >> 5);
    int q = threadIdx.x & 31;
    ye_one(vr, q, y2, cntENp, adjEN, ye2);
}

__global__ __launch_bounds__(256) void k_ye_o(const uint2* __restrict__ y2,
        const uint2* __restrict__ e2,
        const int* __restrict__ cntENp, const int* __restrict__ adjEN,
        uint2* __restrict__ ye2, float* __restrict__ revacc) {
    int slot = blockIdx.x * 8 + (threadIdx.x >> 5);
    int q = threadIdx.x & 31;
    if (slot < T_ * E_)
        ye_one(slot, q, y2, cntENp, adjEN, ye2);
    else
        o_one(slot - T_ * E_, q, e2, cntENp, adjEN, (float4*)revacc, nullptr, 0);
}

__global__ __launch_bounds__(256) void k_e(const uint2* __restrict__ ye2,
        const float* __restrict__ dVis, const int* __restrict__ cntNE,
        const int* __restrict__ adjNE, uint2* __restrict__ e2,
        const float* __restrict__ x0, float* __restrict__ xsum0,
        float* __restrict__ outnode, int last) {
    int n = blockIdx.x * 8 + (threadIdx.x >> 5);
    int q = threadIdx.x & 31;
    e_work(n, q, ye2, dVis, cntNE, adjNE, e2, x0, xsum0, outnode, last);
}

__global__ __launch_bounds__(256) void k_o(const uint2* __restrict__ e2,
        const int* __restrict__ cntENp, const int* __restrict__ adjEN,
        float* __restrict__ revacc, float* __restrict__ outrev) {
    int e = blockIdx.x * 8 + (threadIdx.x >> 5);
    int q = threadIdx.x & 31;
    o_one(e, q, e2, cntENp, adjEN, (float4*)revacc, (float4*)outrev, 1);
}

// ---------------------------------------------------------------------------
// PROBES: k x the real workload, rows remapped per iteration, shadow outputs.
__global__ __launch_bounds__(256) void k_ye_probe(const uint2* __restrict__ y2,
        const int* __restrict__ cntENp, const int* __restrict__ adjEN,
        uint2* __restrict__ ye_sh) {
    int base = blockIdx.x * 8 + (threadIdx.x >> 5);
    int q = threadIdx.x & 31;
    for (int r = 0; r < 12; ++r) {
        int vr = (base + r * 683) & (T_ * E_ - 1);
        ye_one(vr, q, y2, cntENp, adjEN, ye_sh);
    }
}

__global__ __launch_bounds__(256) void k_e_probe(const uint2* __restrict__ ye2,
        const float* __restrict__ dVis, const int* __restrict__ cntNE,
        const int* __restrict__ adjNE, uint2* __restrict__ e_sh,
        const float* __restrict__ x0, float* __restrict__ xsum_sh) {
    int base = blockIdx.x * 8 + (threadIdx.x >> 5);
    int q = threadIdx.x & 31;
    for (int r = 0; r < 12; ++r) {
        int n = (base + r * 337) & (N_ - 1);
        e_work(n, q, ye2, dVis, cntNE, adjNE, e_sh, x0, xsum_sh, nullptr, 0);
    }
}

__global__ __launch_bounds__(256) void k_o_probe(const uint2* __restrict__ e2,
        const int* __restrict__ cntENp, const int* __restrict__ adjEN,
        float* __restrict__ rev_sh) {
    int base = blockIdx.x * 8 + (threadIdx.x >> 5);
    int q = threadIdx.x & 31;
    for (int r = 0; r < 12; ++r) {
        int e = (base + r * 337) & (E_ - 1);
        o_one(e, q, e2, cntENp, adjEN, (float4*)rev_sh, nullptr, 0);
    }
}

// ---------------------------------------------------------------------------
extern "C" void kernel_launch(void* const* d_in, const int* in_sizes, int n_in,
                              void* d_out, int out_size, void* d_ws, size_t ws_size,
                              hipStream_t stream) {
    const float* x = (const float*)d_in[0];
    const float* H = (const float*)d_in[1];
    const float* W = (const float*)d_in[2];
    const float* b = (const float*)d_in[3];
    float* outnode = (float*)d_out;
    float* outrev  = (float*)d_out + (size_t)N_ * D_;

    char* p = (char*)d_ws;
    auto alloc = [&](size_t bytes) {
        char* r = p;
        p += (bytes + 255) & ~(size_t)255;
        return r;
    };
    float* dVis   = (float*)alloc((size_t)T_ * N_ * 4);
    int*   cntNE  = (int*)  alloc((size_t)T_ * N_ * 4);
    int*   cntENp = (int*)  alloc((size_t)T_ * E_ * 16 * 4);
    int*   adjNE  = (int*)  alloc((size_t)T_ * N_ * CAP * 4);
    int*   adjEN  = (int*)  alloc((size_t)T_ * E_ * CAP * 4);
    uint2* y2     = (uint2*)alloc((size_t)T_ * N_ * D_ * 2);
    uint2* ye2    = (uint2*)alloc((size_t)T_ * E_ * D_ * 2);
    uint2* e2     = (uint2*)alloc((size_t)T_ * N_ * D_ * 2);
    float* xsum0  = (float*)alloc((size_t)N_ * D_ * 4);
    float* revacc = (float*)alloc((size_t)E_ * D_ * 4);
    // probe shadows
    float* dVis_sh  = (float*)alloc((size_t)T_ * N_ * 4);
    int*   cntNE_sh = (int*)  alloc((size_t)T_ * N_ * 4);
    int*   adjNE_sh = (int*)  alloc((size_t)T_ * N_ * CAP * 4);
    uint2* ye_sh    = (uint2*)alloc((size_t)T_ * E_ * D_ * 2);
    uint2* e_sh     = (uint2*)alloc((size_t)T_ * N_ * D_ * 2);
    float* xsum_sh  = (float*)alloc((size_t)N_ * D_ * 4);
    float* rev_sh   = (float*)alloc((size_t)E_ * D_ * 4);

    // real 8-node chain (identical to round 9)
    k_scan<<<T_ * N_ / 4, 256, 0, stream>>>(H, dVis, cntNE, adjNE, cntENp);
    k_inv_xw0<<<2048 + 256, 256, 0, stream>>>(cntNE, adjNE, cntENp, adjEN,
                                              x, W, b, dVis, y2);
    k_ye<<<T_ * E_ / 8, 256, 0, stream>>>(y2, cntENp, adjEN, ye2);
    k_e<<<N_ / 8, 256, 0, stream>>>(ye2, dVis, cntNE, adjNE, e2, x, xsum0,
                                    outnode, 0);
    k_xw1<<<256, 256, 0, stream>>>(xsum0, W, b, dVis, y2);
    k_ye_o<<<(T_ * E_ + E_) / 8, 256, 0, stream>>>(y2, e2, cntENp, adjEN,
                                                   ye2, revacc);
    k_e<<<N_ / 8, 256, 0, stream>>>(ye2, dVis, cntNE, adjNE, e2, x, xsum0,
                                    outnode, 1);
    k_o<<<E_ / 8, 256, 0, stream>>>(e2, cntENp, adjEN, revacc, outrev);

    // measurement probes (shadow outputs; do not affect d_out)
    k_scan_probe<<<T_ * N_ / 4, 256, 0, stream>>>(H, dVis_sh, cntNE_sh, adjNE_sh);
    k_ye_probe<<<T_ * E_ / 8, 256, 0, stream>>>(y2, cntENp, adjEN, ye_sh);
    k_e_probe<<<N_ / 8, 256, 0, stream>>>(ye2, dVis, cntNE, adjNE, e_sh, x, xsum_sh);
    k_o_probe<<<E_ / 8, 256, 0, stream>>>(e2, cntENp, adjEN, rev_sh);
}

// Round 11
// 90.519 us; speedup vs baseline: 4.6801x; 4.6801x over previous
//
#include <hip/hip_runtime.h>

#define T_ 2
#define N_ 4096
#define E_ 4096
#define D_ 128
#define CAP 64        // max stored nnz per row/col
#define PAD 16        // unrolled gather width; P(c>16) ~ 0.3% of rows -> tail loop
#define SENT 8192     // sentinel global row id -> zeroed extra row in gathered bufs
#define DB2 (D_ / 4)  // 32 uint2 (4 bf16) per feature row
#define D4 (D_ / 4)

// ---------------------------------------------------------------------------
// bf16 helpers
__device__ __forceinline__ unsigned f2bf_rne(float f) {
    unsigned u = __float_as_uint(f);
    return (u + 0x7FFFu + ((u >> 16) & 1u)) >> 16;
}
__device__ __forceinline__ unsigned pack2(float lo, float hi) {
    return f2bf_rne(lo) | (f2bf_rne(hi) << 16);
}
__device__ __forceinline__ void acc_bf4(float4& s, uint2 a) {
    s.x += __uint_as_float(a.x << 16);
    s.y += __uint_as_float(a.x & 0xFFFF0000u);
    s.z += __uint_as_float(a.y << 16);
    s.w += __uint_as_float(a.y & 0xFFFF0000u);
}

// ---------------------------------------------------------------------------
// scan: streaming pass over H, one wave per row. Emits GLOBAL edge ids
// (t*E+e) padded to PAD with SENT. Also: pre-inits adjEN first-16 to SENT,
// zeroes padded counters, zeroes the 3 sentinel rows.
__global__ __launch_bounds__(256) void k_scan(const float* __restrict__ H,
        float* __restrict__ dVis, int* __restrict__ cntNE,
        int* __restrict__ adjNE, int* __restrict__ cntENp,
        int* __restrict__ adjEN,
        uint2* __restrict__ y2, uint2* __restrict__ ye2, uint2* __restrict__ e2) {
    int row = blockIdx.x * 4 + (threadIdx.x >> 6);   // t*N + n in [0,8192)
    int lane = threadIdx.x & 63;
    int t = row >> 12;
    // housekeeping (overwritten by invert where counts reach)
    if (lane < PAD) adjEN[(size_t)row * CAP + lane] = SENT;
    else if (lane == PAD) cntENp[row * 16] = 0;
    if (blockIdx.x == 0 && threadIdx.x < 32) {
        uint2 z = {0u, 0u};
        y2[(size_t)SENT * DB2 + threadIdx.x] = z;
        ye2[(size_t)SENT * DB2 + threadIdx.x] = z;
        e2[(size_t)SENT * DB2 + threadIdx.x] = z;
    }
    const float4* row4 = (const float4*)(H + (size_t)row * E_);
    unsigned long long mask = 0;
    #pragma unroll
    for (int i = 0; i < 16; ++i) {
        float4 v = row4[i * 64 + lane];              // 1KB/instr coalesced
        unsigned mm = 0;
        if (v.x != 0.0f) mm |= 1u;
        if (v.y != 0.0f) mm |= 2u;
        if (v.z != 0.0f) mm |= 4u;
        if (v.w != 0.0f) mm |= 8u;
        mask |= (unsigned long long)mm << (i * 4);
    }
    int cnt = __popcll(mask);
    int incl = cnt;
    #pragma unroll
    for (int off = 1; off < 64; off <<= 1) {
        int u = __shfl_up(incl, off);
        if (lane >= off) incl += u;
    }
    int pos = incl - cnt;                             // exclusive prefix
    int total = __shfl(incl, 63);
    int* adjrow = adjNE + (size_t)row * CAP;
    unsigned long long m = mask;
    while (m) {
        int bpos = __builtin_ctzll(m);
        m &= m - 1;
        int e = ((bpos >> 2) << 8) + lane * 4 + (bpos & 3);
        if (pos < CAP) adjrow[pos] = t * E_ + e;      // global edge id
        ++pos;
    }
    if (lane < PAD - total) adjrow[total + lane] = SENT;   // pad to 16
    if (lane == 63) {
        cntNE[row] = total < CAP ? total : CAP;
        dVis[row] = total > 0 ? rsqrtf((float)total) : 0.0f;
    }
}

// ---------------------------------------------------------------------------
// xw tile body (unchanged math; bf16 out)
__device__ __forceinline__ void xw_tile(int slot, int l,
        const float* __restrict__ xsrc, const float* __restrict__ W,
        const float* __restrict__ b, const float* __restrict__ dVis,
        uint2* __restrict__ y2, float* s_xs, float* s_ws) {
    int t = slot >> 7;
    int nb = (slot >> 1) & 63, ob = slot & 1;
    int n0 = nb * 64, o0 = ob * 64;
    int tid = threadIdx.x;
    int tx = tid & 15, ty = tid >> 4;
    const float* Wg = W + ((size_t)(l * T_ + t) * D_ + o0) * D_;
    const float* xg = xsrc + (size_t)n0 * D_;
    float acc[4][4] = {};
    for (int kc = 0; kc < 4; ++kc) {
        __syncthreads();
        for (int i = tid; i < 512; i += 256) {
            int r = i >> 3, k4 = i & 7;
            *(float4*)(s_xs + r * 36 + k4 * 4) =
                *(const float4*)(xg + (size_t)r * D_ + kc * 32 + k4 * 4);
            int k4s = k4 ^ ((r >> 2) & 7);
            *(float4*)(s_ws + r * 32 + k4s * 4) =
                *(const float4*)(Wg + (size_t)r * D_ + kc * 32 + k4 * 4);
        }
        __syncthreads();
        #pragma unroll
        for (int k4 = 0; k4 < 8; ++k4) {
            float4 xv[4], wv[4];
            #pragma unroll
            for (int rr = 0; rr < 4; ++rr)
                xv[rr] = *(const float4*)(s_xs + (ty * 4 + rr) * 36 + k4 * 4);
            int k4s = k4 ^ (tx & 7);
            #pragma unroll
            for (int cc = 0; cc < 4; ++cc)
                wv[cc] = *(const float4*)(s_ws + (tx * 4 + cc) * 32 + k4s * 4);
            #pragma unroll
            for (int rr = 0; rr < 4; ++rr)
                #pragma unroll
                for (int cc = 0; cc < 4; ++cc)
                    acc[rr][cc] += xv[rr].x * wv[cc].x + xv[rr].y * wv[cc].y
                                 + xv[rr].z * wv[cc].z + xv[rr].w * wv[cc].w;
        }
    }
    const float* bg = b + (size_t)(l * T_ + t) * D_;
    float4 bv = *(const float4*)(bg + o0 + tx * 4);
    #pragma unroll
    for (int rr = 0; rr < 4; ++rr) {
        int n = n0 + ty * 4 + rr;
        float s = dVis[t * N_ + n];
        uint2 ov;
        ov.x = pack2(s * (acc[rr][0] + bv.x), s * (acc[rr][1] + bv.y));
        ov.y = pack2(s * (acc[rr][2] + bv.z), s * (acc[rr][3] + bv.w));
        y2[(size_t)(t * N_ + n) * DB2 + (o0 >> 2) + tx] = ov;
    }
}

// fused invert + xw(l=0)
__global__ __launch_bounds__(256) void k_inv_xw0(const int* __restrict__ cntNE,
        const int* __restrict__ adjNE, int* __restrict__ cntENp,
        int* __restrict__ adjEN,
        const float* __restrict__ x, const float* __restrict__ W,
        const float* __restrict__ b, const float* __restrict__ dVis,
        uint2* __restrict__ y2) {
    __shared__ float s_xs[64 * 36];
    __shared__ float s_ws[64 * 32];
    int bid = blockIdx.x;
    if (bid < 2048) {
        int row = bid * 4 + (threadIdx.x >> 6);
        int lane = threadIdx.x & 63;
        int c = cntNE[row];
        if (lane < c) {
            int eg = adjNE[(size_t)row * CAP + lane];   // global edge id
            int slot = atomicAdd(&cntENp[eg * 16], 1);
            if (slot < CAP) adjEN[(size_t)eg * CAP + slot] = row;  // global node id
        }
    } else {
        xw_tile(bid - 2048, 0, x, W, b, dVis, y2, s_xs, s_ws);
    }
}

__global__ __launch_bounds__(256) void k_xw1(const float* __restrict__ xsrc,
        const float* __restrict__ W, const float* __restrict__ b,
        const float* __restrict__ dVis, uint2* __restrict__ y2) {
    __shared__ float s_xs[64 * 36];
    __shared__ float s_ws[64 * 32];
    xw_tile(blockIdx.x, 1, xsrc, W, b, dVis, y2, s_xs, s_ws);
}

// ---------------------------------------------------------------------------
// unrolled-16 gather: 4 int4 index loads issued together, 16 gathers issued
// together -> ONE dependent latency round. Sentinel rows contribute +0.0.
__device__ __forceinline__ float4 gather16(const uint2* __restrict__ src,
        const int* __restrict__ row, int c, int q) {
    const int4* r4 = (const int4*)row;
    int4 i0 = r4[0], i1 = r4[1], i2 = r4[2], i3 = r4[3];
    float4 s = {0.f, 0.f, 0.f, 0.f};
    acc_bf4(s, src[(size_t)i0.x * DB2 + q]);
    acc_bf4(s, src[(size_t)i0.y * DB2 + q]);
    acc_bf4(s, src[(size_t)i0.z * DB2 + q]);
    acc_bf4(s, src[(size_t)i0.w * DB2 + q]);
    acc_bf4(s, src[(size_t)i1.x * DB2 + q]);
    acc_bf4(s, src[(size_t)i1.y * DB2 + q]);
    acc_bf4(s, src[(size_t)i1.z * DB2 + q]);
    acc_bf4(s, src[(size_t)i1.w * DB2 + q]);
    acc_bf4(s, src[(size_t)i2.x * DB2 + q]);
    acc_bf4(s, src[(size_t)i2.y * DB2 + q]);
    acc_bf4(s, src[(size_t)i2.z * DB2 + q]);
    acc_bf4(s, src[(size_t)i2.w * DB2 + q]);
    acc_bf4(s, src[(size_t)i3.x * DB2 + q]);
    acc_bf4(s, src[(size_t)i3.y * DB2 + q]);
    acc_bf4(s, src[(size_t)i3.z * DB2 + q]);
    acc_bf4(s, src[(size_t)i3.w * DB2 + q]);
    for (int j = PAD; j < c; ++j)                 // rare tail (P ~ 0.3%/row)
        acc_bf4(s, src[(size_t)row[j] * DB2 + q]);
    return s;
}

__device__ __forceinline__ void ye_one(int vr, int q, const uint2* __restrict__ y2,
        const int* __restrict__ cntENp, const int* __restrict__ adjEN,
        uint2* __restrict__ ye2) {
    int c = cntENp[vr * 16];
    if (c > CAP) c = CAP;
    float dE = c > 0 ? 1.0f / (float)c : 0.0f;
    float4 s = gather16(y2, adjEN + (size_t)vr * CAP, c, q);
    uint2 o;
    o.x = pack2(dE * s.x, dE * s.y);
    o.y = pack2(dE * s.z, dE * s.w);
    ye2[(size_t)vr * DB2 + q] = o;
}

// o body, t-split: thread handles one (t,e,q); cross-t sum via shfl_xor(32).
__device__ __forceinline__ void o_body(int e, int t, int q,
        const uint2* __restrict__ e2, const int* __restrict__ cntENp,
        const int* __restrict__ adjEN, float* __restrict__ revacc,
        float* __restrict__ outrev, int last) {
    int r = t * E_ + e;
    int c = cntENp[r * 16];
    if (c > CAP) c = CAP;
    float dE = c > 0 ? 1.0f / (float)c : 0.0f;
    float4 s = gather16(e2, adjEN + (size_t)r * CAP, c, q);
    float4 a = {dE * s.x, dE * s.y, dE * s.z, dE * s.w};
    float4 oth;
    oth.x = __shfl_xor(a.x, 32);
    oth.y = __shfl_xor(a.y, 32);
    oth.z = __shfl_xor(a.z, 32);
    oth.w = __shfl_xor(a.w, 32);
    if (t == 0) {
        float4 tot = {a.x + oth.x, a.y + oth.y, a.z + oth.z, a.w + oth.w};
        size_t i = (size_t)e * D4 + q;
        if (!last) ((float4*)revacc)[i] = tot;
        else {
            float4 ra = ((const float4*)revacc)[i];
            float4 o = {(ra.x + tot.x) * 0.5f, (ra.y + tot.y) * 0.5f,
                        (ra.z + tot.z) * 0.5f, (ra.w + tot.w) * 0.5f};
            ((float4*)outrev)[i] = o;
        }
    }
}

// ---------------------------------------------------------------------------
// ye layer 0: 8 rows / block, grid 1024.
__global__ __launch_bounds__(256) void k_ye(const uint2* __restrict__ y2,
        const int* __restrict__ cntENp, const int* __restrict__ adjEN,
        uint2* __restrict__ ye2) {
    int vr = blockIdx.x * 8 + (threadIdx.x >> 5);
    int q = threadIdx.x & 31;
    ye_one(vr, q, y2, cntENp, adjEN, ye2);
}

// ye layer 1 + o layer 0 fused: blocks [0,1024) ye, [1024,2048) o (t-split).
__global__ __launch_bounds__(256) void k_ye_o(const uint2* __restrict__ y2,
        const uint2* __restrict__ e2,
        const int* __restrict__ cntENp, const int* __restrict__ adjEN,
        uint2* __restrict__ ye2, float* __restrict__ revacc) {
    int bid = blockIdx.x;
    if (bid < 1024) {
        int vr = bid * 8 + (threadIdx.x >> 5);
        int q = threadIdx.x & 31;
        ye_one(vr, q, y2, cntENp, adjEN, ye2);
    } else {
        int tid = threadIdx.x;
        int q = tid & 31, t = (tid >> 5) & 1;
        int e = (bid - 1024) * 4 + (tid >> 6);
        o_body(e, t, q, e2, cntENp, adjEN, revacc, nullptr, 0);
    }
}

// e: t-split, 4 nodes / block, grid 1024. Thread (t,n,q) gathers edges of
// (t,n), stores e2 row; xnew = sum_t via shfl_xor(32); t==0 writes node out.
__global__ __launch_bounds__(256) void k_e(const uint2* __restrict__ ye2,
        const float* __restrict__ dVis, const int* __restrict__ cntNE,
        const int* __restrict__ adjNE, uint2* __restrict__ e2,
        const float* __restrict__ x0, float* __restrict__ xsum0,
        float* __restrict__ outnode, int last) {
    int tid = threadIdx.x;
    int q = tid & 31, t = (tid >> 5) & 1;
    int n = blockIdx.x * 4 + (tid >> 6);
    int r = t * N_ + n;
    int c = cntNE[r];
    float4 s = gather16(ye2, adjNE + (size_t)r * CAP, c, q);
    float dv = dVis[r];
    float4 ev;
    ev.x = dv * s.x; ev.x = ev.x >= 0.f ? ev.x : 0.01f * ev.x;
    ev.y = dv * s.y; ev.y = ev.y >= 0.f ? ev.y : 0.01f * ev.y;
    ev.z = dv * s.z; ev.z = ev.z >= 0.f ? ev.z : 0.01f * ev.z;
    ev.w = dv * s.w; ev.w = ev.w >= 0.f ? ev.w : 0.01f * ev.w;
    uint2 ep;
    ep.x = pack2(ev.x, ev.y);
    ep.y = pack2(ev.z, ev.w);
    e2[(size_t)r * DB2 + q] = ep;
    float4 oth;
    oth.x = __shfl_xor(ev.x, 32);
    oth.y = __shfl_xor(ev.y, 32);
    oth.z = __shfl_xor(ev.z, 32);
    oth.w = __shfl_xor(ev.w, 32);
    if (t == 0) {
        float4 xnew = {ev.x + oth.x, ev.y + oth.y, ev.z + oth.z, ev.w + oth.w};
        size_t i = (size_t)n * D4 + q;
        if (!last) ((float4*)xsum0)[i] = xnew;
        else {
            float4 xv = ((const float4*)x0)[i];
            float4 xs = ((const float4*)xsum0)[i];
            float4 o = {(xv.x + xs.x + xnew.x) * (1.0f / 3.0f),
                        (xv.y + xs.y + xnew.y) * (1.0f / 3.0f),
                        (xv.z + xs.z + xnew.z) * (1.0f / 3.0f),
                        (xv.w + xs.w + xnew.w) * (1.0f / 3.0f)};
            ((float4*)outnode)[i] = o;
        }
    }
}

// o last layer: t-split, 4 edges / block, grid 1024.
__global__ __launch_bounds__(256) void k_o(const uint2* __restrict__ e2,
        const int* __restrict__ cntENp, const int* __restrict__ adjEN,
        float* __restrict__ revacc, float* __restrict__ outrev) {
    int tid = threadIdx.x;
    int q = tid & 31, t = (tid >> 5) & 1;
    int e = blockIdx.x * 4 + (tid >> 6);
    o_body(e, t, q, e2, cntENp, adjEN, revacc, outrev, 1);
}

// ---------------------------------------------------------------------------
extern "C" void kernel_launch(void* const* d_in, const int* in_sizes, int n_in,
                              void* d_out, int out_size, void* d_ws, size_t ws_size,
                              hipStream_t stream) {
    const float* x = (const float*)d_in[0];
    const float* H = (const float*)d_in[1];
    const float* W = (const float*)d_in[2];
    const float* b = (const float*)d_in[3];
    float* outnode = (float*)d_out;
    float* outrev  = (float*)d_out + (size_t)N_ * D_;

    char* p = (char*)d_ws;
    auto alloc = [&](size_t bytes) {
        char* r = p;
        p += (bytes + 255) & ~(size_t)255;
        return r;
    };
    float* dVis   = (float*)alloc((size_t)T_ * N_ * 4);
    int*   cntNE  = (int*)  alloc((size_t)T_ * N_ * 4);
    int*   cntENp = (int*)  alloc((size_t)T_ * E_ * 16 * 4);
    int*   adjNE  = (int*)  alloc((size_t)T_ * N_ * CAP * 4);
    int*   adjEN  = (int*)  alloc((size_t)T_ * E_ * CAP * 4);
    uint2* y2     = (uint2*)alloc((size_t)(SENT + 1) * D_ * 2);  // +sentinel row
    uint2* ye2    = (uint2*)alloc((size_t)(SENT + 1) * D_ * 2);
    uint2* e2     = (uint2*)alloc((size_t)(SENT + 1) * D_ * 2);
    float* xsum0  = (float*)alloc((size_t)N_ * D_ * 4);
    float* revacc = (float*)alloc((size_t)E_ * D_ * 4);

    k_scan<<<T_ * N_ / 4, 256, 0, stream>>>(H, dVis, cntNE, adjNE, cntENp,
                                            adjEN, y2, ye2, e2);
    k_inv_xw0<<<2048 + 256, 256, 0, stream>>>(cntNE, adjNE, cntENp, adjEN,
                                              x, W, b, dVis, y2);
    k_ye<<<T_ * E_ / 8, 256, 0, stream>>>(y2, cntENp, adjEN, ye2);
    k_e<<<N_ / 4, 256, 0, stream>>>(ye2, dVis, cntNE, adjNE, e2, x, xsum0,
                                    outnode, 0);
    k_xw1<<<256, 256, 0, stream>>>(xsum0, W, b, dVis, y2);
    k_ye_o<<<2048, 256, 0, stream>>>(y2, e2, cntENp, adjEN, ye2, revacc);
    k_e<<<N_ / 4, 256, 0, stream>>>(ye2, dVis, cntNE, adjNE, e2, x, xsum0,
                                    outnode, 1);
    k_o<<<E_ / 4, 256, 0, stream>>>(e2, cntENp, adjEN, revacc, outrev);
}

// Round 12
// 86.083 us; speedup vs baseline: 4.9213x; 1.0515x over previous
//
#include <hip/hip_runtime.h>

#define T_ 2
#define N_ 4096
#define E_ 4096
#define D_ 128
#define CAP 64        // max stored nnz per row/col
#define PAD 16        // unrolled gather width; tail loop handles c>16 (~0.3% rows)
#define SENT 8192     // sentinel row id -> zeroed extra row, dVis[SENT]=0
#define UPR 64        // uints per bf16 feature row (128 bf16 = 64 uints)

// ---------------------------------------------------------------------------
__device__ __forceinline__ unsigned f2bf_rne(float f) {
    unsigned u = __float_as_uint(f);
    return (u + 0x7FFFu + ((u >> 16) & 1u)) >> 16;
}
__device__ __forceinline__ unsigned pack2(float lo, float hi) {
    return f2bf_rne(lo) | (f2bf_rne(hi) << 16);
}

// 64-lane gathers: lane q covers bf16 elems (2q, 2q+1) of each row (4B/lane).
// 4 int4 index loads + 16 row-loads issued together -> one latency round.
__device__ __forceinline__ float2 gather64(const unsigned* __restrict__ src,
        const int* __restrict__ row, int c, int lane) {
    const int4* r4 = (const int4*)row;
    int4 i0 = r4[0], i1 = r4[1], i2 = r4[2], i3 = r4[3];
    float sx = 0.f, sy = 0.f;
#define G1(id) { unsigned v = src[(size_t)(id) * UPR + lane]; \
                 sx += __uint_as_float(v << 16); \
                 sy += __uint_as_float(v & 0xFFFF0000u); }
    G1(i0.x) G1(i0.y) G1(i0.z) G1(i0.w)
    G1(i1.x) G1(i1.y) G1(i1.z) G1(i1.w)
    G1(i2.x) G1(i2.y) G1(i2.z) G1(i2.w)
    G1(i3.x) G1(i3.y) G1(i3.z) G1(i3.w)
    for (int j = PAD; j < c; ++j) G1(row[j])
#undef G1
    float2 r = {sx, sy};
    return r;
}

__device__ __forceinline__ float2 gather64w(const unsigned* __restrict__ src,
        const float* __restrict__ wgt, const int* __restrict__ row, int c, int lane) {
    const int4* r4 = (const int4*)row;
    int4 i0 = r4[0], i1 = r4[1], i2 = r4[2], i3 = r4[3];
    float sx = 0.f, sy = 0.f;
#define G1(id) { unsigned v = src[(size_t)(id) * UPR + lane]; float w = wgt[id]; \
                 sx += w * __uint_as_float(v << 16); \
                 sy += w * __uint_as_float(v & 0xFFFF0000u); }
    G1(i0.x) G1(i0.y) G1(i0.z) G1(i0.w)
    G1(i1.x) G1(i1.y) G1(i1.z) G1(i1.w)
    G1(i2.x) G1(i2.y) G1(i2.z) G1(i2.w)
    G1(i3.x) G1(i3.y) G1(i3.z) G1(i3.w)
    for (int j = PAD; j < c; ++j) G1(row[j])
#undef G1
    float2 r = {sx, sy};
    return r;
}

// ---------------------------------------------------------------------------
// xw tile: y[t,n0:+64, o0:+64] = xsrc @ W[l,t]^T + b (UNSCALED; dVis folded
// into the weighted ye gather). bf16 out.
__device__ __forceinline__ void xw_tile(int slot, int l,
        const float* __restrict__ xsrc, const float* __restrict__ W,
        const float* __restrict__ b, uint2* __restrict__ y2,
        float* s_xs, float* s_ws) {
    int t = slot >> 7;
    int nb = (slot >> 1) & 63, ob = slot & 1;
    int n0 = nb * 64, o0 = ob * 64;
    int tid = threadIdx.x;
    int tx = tid & 15, ty = tid >> 4;
    const float* Wg = W + ((size_t)(l * T_ + t) * D_ + o0) * D_;
    const float* xg = xsrc + (size_t)n0 * D_;
    float acc[4][4] = {};
    for (int kc = 0; kc < 4; ++kc) {
        __syncthreads();
        for (int i = tid; i < 512; i += 256) {
            int r = i >> 3, k4 = i & 7;
            *(float4*)(s_xs + r * 36 + k4 * 4) =
                *(const float4*)(xg + (size_t)r * D_ + kc * 32 + k4 * 4);
            int k4s = k4 ^ ((r >> 2) & 7);
            *(float4*)(s_ws + r * 32 + k4s * 4) =
                *(const float4*)(Wg + (size_t)r * D_ + kc * 32 + k4 * 4);
        }
        __syncthreads();
        #pragma unroll
        for (int k4 = 0; k4 < 8; ++k4) {
            float4 xv[4], wv[4];
            #pragma unroll
            for (int rr = 0; rr < 4; ++rr)
                xv[rr] = *(const float4*)(s_xs + (ty * 4 + rr) * 36 + k4 * 4);
            int k4s = k4 ^ (tx & 7);
            #pragma unroll
            for (int cc = 0; cc < 4; ++cc)
                wv[cc] = *(const float4*)(s_ws + (tx * 4 + cc) * 32 + k4s * 4);
            #pragma unroll
            for (int rr = 0; rr < 4; ++rr)
                #pragma unroll
                for (int cc = 0; cc < 4; ++cc)
                    acc[rr][cc] += xv[rr].x * wv[cc].x + xv[rr].y * wv[cc].y
                                 + xv[rr].z * wv[cc].z + xv[rr].w * wv[cc].w;
        }
    }
    const float* bg = b + (size_t)(l * T_ + t) * D_;
    float4 bv = *(const float4*)(bg + o0 + tx * 4);
    #pragma unroll
    for (int rr = 0; rr < 4; ++rr) {
        int n = n0 + ty * 4 + rr;
        uint2 ov;
        ov.x = pack2(acc[rr][0] + bv.x, acc[rr][1] + bv.y);
        ov.y = pack2(acc[rr][2] + bv.z, acc[rr][3] + bv.w);
        y2[(size_t)(t * N_ + n) * (UPR / 2) + (o0 >> 2) + tx] = ov;
    }
}

// ---------------------------------------------------------------------------
// node 1: scan (blocks 0-2047, HBM-bound) || xw layer 0 (blocks 2048-2303,
// VALU/LDS-bound, depends only on inputs). Scan also: adjEN sentinel prefill,
// counter zero, sentinel-row zero, dVis[SENT]=0.
__global__ __launch_bounds__(256) void k_scan_xw0(const float* __restrict__ H,
        float* __restrict__ dVis, int* __restrict__ cntNE,
        int* __restrict__ adjNE, int* __restrict__ cntENp,
        int* __restrict__ adjEN,
        const float* __restrict__ x, const float* __restrict__ W,
        const float* __restrict__ b, uint2* __restrict__ y2,
        unsigned* __restrict__ y2u, unsigned* __restrict__ ye2u,
        unsigned* __restrict__ e2u) {
    __shared__ float s_xs[64 * 36];
    __shared__ float s_ws[64 * 32];
    int bid = blockIdx.x;
    if (bid >= 2048) {
        xw_tile(bid - 2048, 0, x, W, b, y2, s_xs, s_ws);
        return;
    }
    int row = bid * 4 + (threadIdx.x >> 6);
    int lane = threadIdx.x & 63;
    int t = row >> 12;
    if (lane < PAD) adjEN[(size_t)row * CAP + lane] = SENT;
    else if (lane == PAD) cntENp[row * 16] = 0;
    if (bid == 0 && threadIdx.x < 64) {
        y2u[(size_t)SENT * UPR + threadIdx.x] = 0u;
        ye2u[(size_t)SENT * UPR + threadIdx.x] = 0u;
        e2u[(size_t)SENT * UPR + threadIdx.x] = 0u;
        if (threadIdx.x == 0) dVis[SENT] = 0.0f;
    }
    const float4* row4 = (const float4*)(H + (size_t)row * E_);
    unsigned long long mask = 0;
    #pragma unroll
    for (int i = 0; i < 16; ++i) {
        float4 v = row4[i * 64 + lane];
        unsigned mm = 0;
        if (v.x != 0.0f) mm |= 1u;
        if (v.y != 0.0f) mm |= 2u;
        if (v.z != 0.0f) mm |= 4u;
        if (v.w != 0.0f) mm |= 8u;
        mask |= (unsigned long long)mm << (i * 4);
    }
    int cnt = __popcll(mask);
    int incl = cnt;
    #pragma unroll
    for (int off = 1; off < 64; off <<= 1) {
        int u = __shfl_up(incl, off);
        if (lane >= off) incl += u;
    }
    int pos = incl - cnt;
    int total = __shfl(incl, 63);
    int* adjrow = adjNE + (size_t)row * CAP;
    unsigned long long m = mask;
    while (m) {
        int bpos = __builtin_ctzll(m);
        m &= m - 1;
        int e = ((bpos >> 2) << 8) + lane * 4 + (bpos & 3);
        if (pos < CAP) adjrow[pos] = t * E_ + e;      // global edge id
        ++pos;
    }
    if (lane < PAD - total) adjrow[total + lane] = SENT;
    if (lane == 63) {
        cntNE[row] = total < CAP ? total : CAP;
        dVis[row] = total > 0 ? rsqrtf((float)total) : 0.0f;
    }
}

// node 2: invert adjNE -> adjEN (atomic append on padded counters)
__global__ __launch_bounds__(256) void k_inv(const int* __restrict__ cntNE,
        const int* __restrict__ adjNE, int* __restrict__ cntENp,
        int* __restrict__ adjEN) {
    int row = blockIdx.x * 4 + (threadIdx.x >> 6);
    int lane = threadIdx.x & 63;
    int c = cntNE[row];
    if (lane < c) {
        int eg = adjNE[(size_t)row * CAP + lane];
        int slot = atomicAdd(&cntENp[eg * 16], 1);
        if (slot < CAP) adjEN[(size_t)eg * CAP + slot] = row;
    }
}

// ---------------------------------------------------------------------------
// ye: dVis-weighted gather of unscaled y. 64-lane units, 4/block, grid 2048
// (8192 waves = 32/CU).
__global__ __launch_bounds__(256) void k_ye_w(const unsigned* __restrict__ y2u,
        const float* __restrict__ dVis, const int* __restrict__ cntENp,
        const int* __restrict__ adjEN, unsigned* __restrict__ ye2u) {
    int u = threadIdx.x >> 6, lane = threadIdx.x & 63;
    int vr = blockIdx.x * 4 + u;
    int c = cntENp[vr * 16];
    if (c > CAP) c = CAP;
    float dE = c > 0 ? 1.0f / (float)c : 0.0f;
    float2 g = gather64w(y2u, dVis, adjEN + (size_t)vr * CAP, c, lane);
    ye2u[(size_t)vr * UPR + lane] = pack2(dE * g.x, dE * g.y);
}

// o unit body (cross-t via LDS; t from u&1, pair = u^1)
__device__ __forceinline__ void o_unit(int e, int u, int lane,
        const unsigned* __restrict__ e2u, const int* __restrict__ cntENp,
        const int* __restrict__ adjEN, float2* __restrict__ revacc2,
        float2* __restrict__ outrev2, int last, float2 (*sb)[64]) {
    int t = u & 1;
    int r = t * E_ + e;
    int c = cntENp[r * 16];
    if (c > CAP) c = CAP;
    float dE = c > 0 ? 1.0f / (float)c : 0.0f;
    float2 g = gather64(e2u, adjEN + (size_t)r * CAP, c, lane);
    float2 a = {dE * g.x, dE * g.y};
    sb[u][lane] = a;
    __syncthreads();
    if (t == 0) {
        float2 o2 = sb[u | 1][lane];
        float2 tot = {a.x + o2.x, a.y + o2.y};
        size_t i = (size_t)e * UPR + lane;
        if (!last) revacc2[i] = tot;
        else {
            float2 ra = revacc2[i];
            float2 o = {(ra.x + tot.x) * 0.5f, (ra.y + tot.y) * 0.5f};
            outrev2[i] = o;
        }
    }
}

// e: 64-lane units (t,n), 4/block (2 nodes x 2t), grid 2048. Cross-t via LDS.
__global__ __launch_bounds__(256) void k_e(const unsigned* __restrict__ ye2u,
        const float* __restrict__ dVis, const int* __restrict__ cntNE,
        const int* __restrict__ adjNE, unsigned* __restrict__ e2u,
        const float* __restrict__ x0, float* __restrict__ xsum0,
        float* __restrict__ outnode, int last) {
    __shared__ float2 sb[4][64];
    int u = threadIdx.x >> 6, lane = threadIdx.x & 63;
    int t = u & 1;
    int n = blockIdx.x * 2 + (u >> 1);
    int r = t * N_ + n;
    int c = cntNE[r];
    float2 g = gather64(ye2u, adjNE + (size_t)r * CAP, c, lane);
    float dv = dVis[r];
    float e0 = dv * g.x; e0 = e0 >= 0.f ? e0 : 0.01f * e0;
    float e1 = dv * g.y; e1 = e1 >= 0.f ? e1 : 0.01f * e1;
    e2u[(size_t)r * UPR + lane] = pack2(e0, e1);
    float2 mine = {e0, e1};
    sb[u][lane] = mine;
    __syncthreads();
    if (t == 0) {
        float2 o2 = sb[u | 1][lane];
        float2 xnew = {e0 + o2.x, e1 + o2.y};
        size_t i = (size_t)n * UPR + lane;
        if (!last) ((float2*)xsum0)[i] = xnew;
        else {
            float2 xv = ((const float2*)x0)[i];
            float2 xs = ((const float2*)xsum0)[i];
            float2 o = {(xv.x + xs.x + xnew.x) * (1.0f / 3.0f),
                        (xv.y + xs.y + xnew.y) * (1.0f / 3.0f)};
            ((float2*)outnode)[i] = o;
        }
    }
}

// node 5: xw layer 1 (blocks 0-255) || o layer 0 (blocks 256-2303) --
// both depend only on e0's outputs (xsum0, e2).
__global__ __launch_bounds__(256) void k_xw1_o0(const float* __restrict__ xsum0,
        const float* __restrict__ W, const float* __restrict__ b,
        uint2* __restrict__ y2,
        const unsigned* __restrict__ e2u, const int* __restrict__ cntENp,
        const int* __restrict__ adjEN, float* __restrict__ revacc) {
    __shared__ float s_xs[64 * 36];
    __shared__ float s_ws[64 * 32];
    __shared__ float2 sb[4][64];
    int bid = blockIdx.x;
    if (bid < 256) {
        xw_tile(bid, 1, xsum0, W, b, y2, s_xs, s_ws);
    } else {
        int u = threadIdx.x >> 6, lane = threadIdx.x & 63;
        int e = (bid - 256) * 2 + (u >> 1);
        o_unit(e, u, lane, e2u, cntENp, adjEN, (float2*)revacc, nullptr, 0, sb);
    }
}

// o last layer: grid 2048.
__global__ __launch_bounds__(256) void k_o(const unsigned* __restrict__ e2u,
        const int* __restrict__ cntENp, const int* __restrict__ adjEN,
        float* __restrict__ revacc, float* __restrict__ outrev) {
    __shared__ float2 sb[4][64];
    int u = threadIdx.x >> 6, lane = threadIdx.x & 63;
    int e = blockIdx.x * 2 + (u >> 1);
    o_unit(e, u, lane, e2u, cntENp, adjEN, (float2*)revacc, (float2*)outrev, 1, sb);
}

// ---------------------------------------------------------------------------
extern "C" void kernel_launch(void* const* d_in, const int* in_sizes, int n_in,
                              void* d_out, int out_size, void* d_ws, size_t ws_size,
                              hipStream_t stream) {
    const float* x = (const float*)d_in[0];
    const float* H = (const float*)d_in[1];
    const float* W = (const float*)d_in[2];
    const float* b = (const float*)d_in[3];
    float* outnode = (float*)d_out;
    float* outrev  = (float*)d_out + (size_t)N_ * D_;

    char* p = (char*)d_ws;
    auto alloc = [&](size_t bytes) {
        char* r = p;
        p += (bytes + 255) & ~(size_t)255;
        return r;
    };
    float*    dVis   = (float*)alloc(((size_t)T_ * N_ + 1) * 4);   // +SENT slot
    int*      cntNE  = (int*)  alloc((size_t)T_ * N_ * 4);
    int*      cntENp = (int*)  alloc((size_t)T_ * E_ * 16 * 4);
    int*      adjNE  = (int*)  alloc((size_t)T_ * N_ * CAP * 4);
    int*      adjEN  = (int*)  alloc((size_t)T_ * E_ * CAP * 4);
    unsigned* y2u    = (unsigned*)alloc((size_t)(SENT + 1) * UPR * 4);
    unsigned* ye2u   = (unsigned*)alloc((size_t)(SENT + 1) * UPR * 4);
    unsigned* e2u    = (unsigned*)alloc((size_t)(SENT + 1) * UPR * 4);
    float*    xsum0  = (float*)alloc((size_t)N_ * D_ * 4);
    float*    revacc = (float*)alloc((size_t)E_ * D_ * 4);

    k_scan_xw0<<<2048 + 256, 256, 0, stream>>>(H, dVis, cntNE, adjNE, cntENp,
            adjEN, x, W, b, (uint2*)y2u, y2u, ye2u, e2u);
    k_inv<<<2048, 256, 0, stream>>>(cntNE, adjNE, cntENp, adjEN);
    k_ye_w<<<2048, 256, 0, stream>>>(y2u, dVis, cntENp, adjEN, ye2u);
    k_e<<<2048, 256, 0, stream>>>(ye2u, dVis, cntNE, adjNE, e2u, x, xsum0,
                                  outnode, 0);
    k_xw1_o0<<<256 + 2048, 256, 0, stream>>>(xsum0, W, b, (uint2*)y2u,
            e2u, cntENp, adjEN, revacc);
    k_ye_w<<<2048, 256, 0, stream>>>(y2u, dVis, cntENp, adjEN, ye2u);
    k_e<<<2048, 256, 0, stream>>>(ye2u, dVis, cntNE, adjNE, e2u, x, xsum0,
                                  outnode, 1);
    k_o<<<2048, 256, 0, stream>>>(e2u, cntENp, adjEN, revacc, outrev);
}